// Round 13
// baseline (384.390 us; speedup 1.0000x reference)
//
#include <hip/hip_runtime.h>
#include <hip/hip_fp16.h>
#include <cstdint>
#include <cstddef>

#define N_NODES_C 100000
#define N_EDGES_C 1250000
#define N_PAIRS_C 200000
#define IN_DIM_C 128
#define HID_C 64

// graph-build geometry
#define NB_S 256
#define BSH 9
#define NPB 512
#define NBKT 196
#define SEG_CAP 8192

typedef _Float16 f16x8 __attribute__((ext_vector_type(8)));
typedef float f32x4 __attribute__((ext_vector_type(4)));

// ---------------- scan (single kernel, M=50176 <= 1024*49) ----------------

__global__ __launch_bounds__(1024) void k_scan_full(const int* __restrict__ in,
                                                    int* __restrict__ outp, int n) {
    __shared__ int sd[1024];
    int tid = threadIdx.x;
    int ipt = (n + 1023) >> 10;
    int base = tid * ipt;
    int s = 0;
    for (int k = 0; k < ipt; ++k) { int idx = base + k; if (idx < n) s += in[idx]; }
    sd[tid] = s;
    __syncthreads();
    for (int off = 1; off < 1024; off <<= 1) {
        int tv = (tid >= off) ? sd[tid - off] : 0;
        __syncthreads();
        sd[tid] += tv;
        __syncthreads();
    }
    int excl = sd[tid] - s;
    for (int k = 0; k < ipt; ++k) {
        int idx = base + k;
        if (idx < n) { int v = in[idx]; outp[idx] = excl; excl += v; }
    }
}

// ---------------- graph build: two-level counting sort ----------------

__global__ __launch_bounds__(256) void k_hist(const int* __restrict__ dst,
                                              int* __restrict__ histT, int e) {
    __shared__ int lh[NBKT];
    int tid = threadIdx.x, k = blockIdx.x;
    if (tid < NBKT) lh[tid] = 0;
    __syncthreads();
    int chunk = (e + NB_S - 1) / NB_S;
    int i0 = k * chunk, i1 = min(i0 + chunk, e);
    for (int i = i0 + tid; i < i1; i += 256) atomicAdd(&lh[dst[i] >> BSH], 1);
    __syncthreads();
    if (tid < NBKT) histT[tid * NB_S + k] = lh[tid];
}

__global__ __launch_bounds__(256) void k_scatter(const int* __restrict__ edges,
                                                 const int* __restrict__ offs,
                                                 int2* __restrict__ staging, int e) {
    __shared__ int cur[NBKT];
    int tid = threadIdx.x, k = blockIdx.x;
    if (tid < NBKT) cur[tid] = offs[tid * NB_S + k];
    __syncthreads();
    int chunk = (e + NB_S - 1) / NB_S;
    int i0 = k * chunk, i1 = min(i0 + chunk, e);
    for (int i = i0 + tid; i < i1; i += 256) {
        int s = edges[i];
        int d = edges[e + i];
        int p = atomicAdd(&cur[d >> BSH], 1);
        staging[p] = make_int2(s, d);
    }
}

__global__ __launch_bounds__(256) void k_bucket_fill(const int2* __restrict__ staging,
        const int* __restrict__ offs, int* __restrict__ rowptr,
        float* __restrict__ invd, int* __restrict__ adj, int n, int e) {
    __shared__ int ldeg[NPB];
    __shared__ int lrow[NPB];
    __shared__ int ps[256];
    __shared__ int lseg[SEG_CAP];
    int tid = threadIdx.x, b = blockIdx.x;
    int n0 = b << BSH;
    int nn = min(NPB, n - n0);
    int segBeg = offs[b * NB_S];
    int segEnd = (b == NBKT - 1) ? e : offs[(b + 1) * NB_S];

    ldeg[tid] = 0; ldeg[tid + 256] = 0;
    __syncthreads();
    for (int i = segBeg + tid; i < segEnd; i += 256)
        atomicAdd(&ldeg[staging[i].y - n0], 1);
    __syncthreads();

    int a0 = ldeg[2 * tid], a1 = ldeg[2 * tid + 1];
    int s = a0 + a1;
    ps[tid] = s;
    __syncthreads();
    for (int off = 1; off < 256; off <<= 1) {
        int t = (tid >= off) ? ps[tid - off] : 0;
        __syncthreads();
        ps[tid] += t;
        __syncthreads();
    }
    int excl = ps[tid] - s;
    lrow[2 * tid] = excl;
    lrow[2 * tid + 1] = excl + a0;
    __syncthreads();

    for (int j = tid; j < nn; j += 256) {
        rowptr[n0 + j] = segBeg + lrow[j];
        int d = ldeg[j];
        invd[n0 + j] = (d > 0) ? (1.0f / (float)d) : 0.0f;
    }
    if (b == NBKT - 1 && tid == 0) rowptr[n] = e;
    __syncthreads();

    for (int i = segBeg + tid; i < segEnd; i += 256) {
        int2 ed = staging[i];
        int p = atomicAdd(&lrow[ed.y - n0], 1);
        if (p < SEG_CAP) lseg[p] = ed.x;
        else adj[segBeg + p] = ed.x;
    }
    __syncthreads();

    int m = segEnd - segBeg; if (m > SEG_CAP) m = SEG_CAP;
    for (int p = tid; p < m; p += 256) adj[segBeg + p] = lseg[p];
}

// ---------------- aggregation ----------------
// fp16-gather, EIGHT NODES PER WAVE (ladder: 50 f32 -> 46 fp16 -> 36 two-node
// -> ~30 four-node -> ~25 this). 8 lanes per node, one 16 B load = 8 cols;
// 8 x 16 B = full 128 B row; one gather instruction serves 8 edge-rows.
// Ladder bottomed here: fewer lanes/node would need 2 loads/lane. Gather
// needs high occupancy (R4) and is memory+issue mixed (R5/R7).

__global__ __launch_bounds__(256) void k_aggregate(const int* __restrict__ rowptr,
        const int* __restrict__ adj, const float* __restrict__ invd,
        const __half* __restrict__ hin16, __half* __restrict__ agg16, int n) {
    int wid = threadIdx.x >> 6, lane = threadIdx.x & 63;
    int node0 = (blockIdx.x * 4 + wid) * 8;   // 8 nodes per wave
    if (node0 >= n) return;
    const int q = lane >> 3;          // eighth 0..7 -> node slot
    const int c8 = (lane & 7) * 8;    // columns c8..c8+7
    int node = node0 + q;
    bool valid = node < n;
    int nodec = valid ? node : n - 1;
    int beg = rowptr[nodec], end = rowptr[nodec + 1];
    float a0 = 0.f, a1 = 0.f, a2 = 0.f, a3 = 0.f;
    float a4 = 0.f, a5 = 0.f, a6 = 0.f, a7 = 0.f;
    for (int e = beg; e < end; e += 8) {
        int idx[8];
        #pragma unroll
        for (int j = 0; j < 8; ++j) {
            int ee = e + j;
            idx[j] = adj[ee < end ? ee : end - 1];
        }
        float4 raw[8];
        #pragma unroll
        for (int j = 0; j < 8; ++j)
            raw[j] = *(const float4*)&hin16[(size_t)idx[j] * HID_C + c8];
        #pragma unroll
        for (int j = 0; j < 8; ++j) {
            union { float4 f; __half2 h[4]; } u;
            u.f = raw[j];
            float2 f0 = __half22float2(u.h[0]);
            float2 f1 = __half22float2(u.h[1]);
            float2 f2 = __half22float2(u.h[2]);
            float2 f3 = __half22float2(u.h[3]);
            bool in = (e + j < end);
            a0 += in ? f0.x : 0.f;  a1 += in ? f0.y : 0.f;
            a2 += in ? f1.x : 0.f;  a3 += in ? f1.y : 0.f;
            a4 += in ? f2.x : 0.f;  a5 += in ? f2.y : 0.f;
            a6 += in ? f3.x : 0.f;  a7 += in ? f3.y : 0.f;
        }
    }
    if (valid) {
        float s = invd[node];
        union { float4 f; __half2 h[4]; } o;
        o.h[0] = __floats2half2_rn(a0 * s, a1 * s);
        o.h[1] = __floats2half2_rn(a2 * s, a3 * s);
        o.h[2] = __floats2half2_rn(a4 * s, a5 * s);
        o.h[3] = __floats2half2_rn(a6 * s, a7 * s);
        *(float4*)&agg16[(size_t)node * HID_C + c8] = o.f;
    }
}

// ---------------- helpers ----------------

__device__ __forceinline__ float4 ld4(const float* p) { return *(const float4*)p; }

// ---------------- k_mm: MFMA fp16 GEMM (enc + layers 0,1) --------------------
// R9 PROVEN core. out16 = fp16(relu(A @ W + b)), K=128, BM=128 x BN=64,
// 4 waves, mfma_f32_16x16x32_f16, 48 KB LDS. A/B staged with the SAME assumed
// k-octet map -> HW k-permutation cancels; C/D col=lane&15, row=(lane>>4)*4+reg.
// SRC 0: A = x (f32, stride 128, converted in staging), W = Ws1 (128x64)
// SRC 1: A = [agg16 | h16] (fp16, stride 64 each), W = [Ws1;Ws2] (64x64 each)

template<int SRC>
__global__ __launch_bounds__(256, 2) void k_mm(
    const float* __restrict__ A1f,
    const __half* __restrict__ A1h, const __half* __restrict__ A2h,
    const float* __restrict__ Ws1, const float* __restrict__ Ws2,
    const float* __restrict__ bias,
    __half* __restrict__ out16, int nrows)
{
    __shared__ __half Ah[128 * 128];  // [row][k-swizzled], 32 KB
    __shared__ __half Bt[64 * 128];   // [col][k-swizzled], 16 KB
    const int t = threadIdx.x;
    const int g0 = blockIdx.x * 128;

    #pragma unroll
    for (int p = 0; p < 8; ++p) {
        int li = p * 256 + t;
        int r = li >> 4;              // 0..127
        int o = li & 15;              // octet
        int g = g0 + r; if (g > nrows - 1) g = nrows - 1;
        f16x8 v;
        if (SRC == 0) {
            const float* src = A1f + (size_t)g * 128 + o * 8;
            float4 f0 = ld4(src), f1 = ld4(src + 4);
            v[0] = (_Float16)f0.x; v[1] = (_Float16)f0.y;
            v[2] = (_Float16)f0.z; v[3] = (_Float16)f0.w;
            v[4] = (_Float16)f1.x; v[5] = (_Float16)f1.y;
            v[6] = (_Float16)f1.z; v[7] = (_Float16)f1.w;
        } else {
            const __half* src = (o < 8) ? (A1h + (size_t)g * 64 + o * 8)
                                        : (A2h + (size_t)g * 64 + (o - 8) * 8);
            v = *(const f16x8*)src;
        }
        *(f16x8*)&Ah[r * 128 + (o ^ (r & 15)) * 8] = v;
    }
    #pragma unroll
    for (int p = 0; p < 32; ++p) {
        int li = p * 256 + t;
        int c = li & 63;
        int k = li >> 6;              // 0..127
        float wv;
        if (SRC == 0) wv = Ws1[k * 64 + c];
        else          wv = (k < 64) ? Ws1[k * 64 + c] : Ws2[(k - 64) * 64 + c];
        Bt[c * 128 + (((k >> 3) ^ (c & 15)) * 8) + (k & 7)] = __float2half(wv);
    }
    __syncthreads();

    const int lane = t & 63;
    const int wid = t >> 6;
    const int R = wid * 32;           // wave's 32-row strip
    const int lr = lane & 15;
    const int lk = lane >> 4;         // octet-within-K-step

    f32x4 acc[2][4];
    #pragma unroll
    for (int fr = 0; fr < 2; ++fr)
        #pragma unroll
        for (int fc = 0; fc < 4; ++fc)
            acc[fr][fc] = (f32x4){0.f, 0.f, 0.f, 0.f};

    #pragma unroll
    for (int ks = 0; ks < 4; ++ks) {
        int o = ks * 4 + lk;          // octet 0..15
        f16x8 af0, af1;
        {
            int r0 = R + lr;
            int r1 = R + 16 + lr;
            af0 = *(const f16x8*)&Ah[r0 * 128 + (o ^ (r0 & 15)) * 8];
            af1 = *(const f16x8*)&Ah[r1 * 128 + (o ^ (r1 & 15)) * 8];
        }
        #pragma unroll
        for (int fc = 0; fc < 4; ++fc) {
            int c = fc * 16 + lr;
            f16x8 bf = *(const f16x8*)&Bt[c * 128 + (o ^ (c & 15)) * 8];
            acc[0][fc] = __builtin_amdgcn_mfma_f32_16x16x32_f16(af0, bf, acc[0][fc], 0, 0, 0);
            acc[1][fc] = __builtin_amdgcn_mfma_f32_16x16x32_f16(af1, bf, acc[1][fc], 0, 0, 0);
        }
    }

    float bv[4];
    #pragma unroll
    for (int fc = 0; fc < 4; ++fc) bv[fc] = bias[fc * 16 + lr];
    #pragma unroll
    for (int fr = 0; fr < 2; ++fr) {
        #pragma unroll
        for (int j = 0; j < 4; ++j) {
            int gr = g0 + R + fr * 16 + lk * 4 + j;
            if (gr < nrows) {
                #pragma unroll
                for (int fc = 0; fc < 4; ++fc) {
                    int col = fc * 16 + lr;
                    float v = fmaxf(acc[fr][fc][j] + bv[fc], 0.f);
                    out16[(size_t)gr * 64 + col] = __float2half(v);
                }
            }
        }
    }
}

// ---------------- k_mm_uv: layer-2 GEMM fused with the UV GEMM ---------------
// R13: layer-2's h was consumed ONLY by k_uvm, and each block already holds
// the full 128x64 h-tile in registers after stage 1. So: sync, write
// bias+relu'd h (same __float2half rounding -> numerically identical) into
// the Ah space re-laid-out [128][64] with k_uvm's o^(r&7) swizzle, restage
// W1 into the Bt space (exactly 16 KB), run the UV stage in-place.
// Kills: one launch + 12.8 MB h write + 12.8 MB h read. LDS stays 48 KB.

__global__ __launch_bounds__(256, 2) void k_mm_uv(
    const __half* __restrict__ A1h, const __half* __restrict__ A2h,
    const float* __restrict__ Ws1, const float* __restrict__ Ws2,
    const float* __restrict__ bias, const float* __restrict__ W1p,
    __half* __restrict__ U16, __half* __restrict__ V16, int nrows)
{
    __shared__ __half Ah[128 * 128];  // stage1: [row][k^sw] 32 KB; stage2: h [128][64]
    __shared__ __half Bt[64 * 128];   // stage1: W [col][k^sw] 16 KB; stage2: W1 [128][64]
    const int t = threadIdx.x;
    const int g0 = blockIdx.x * 128;

    // ---- stage 1: h = relu([agg|h] @ [Wl;Wr] + b)  (identical to k_mm<1>) ----
    #pragma unroll
    for (int p = 0; p < 8; ++p) {
        int li = p * 256 + t;
        int r = li >> 4;
        int o = li & 15;
        int g = g0 + r; if (g > nrows - 1) g = nrows - 1;
        const __half* src = (o < 8) ? (A1h + (size_t)g * 64 + o * 8)
                                    : (A2h + (size_t)g * 64 + (o - 8) * 8);
        f16x8 v = *(const f16x8*)src;
        *(f16x8*)&Ah[r * 128 + (o ^ (r & 15)) * 8] = v;
    }
    #pragma unroll
    for (int p = 0; p < 32; ++p) {
        int li = p * 256 + t;
        int c = li & 63;
        int k = li >> 6;
        float wv = (k < 64) ? Ws1[k * 64 + c] : Ws2[(k - 64) * 64 + c];
        Bt[c * 128 + (((k >> 3) ^ (c & 15)) * 8) + (k & 7)] = __float2half(wv);
    }
    __syncthreads();

    const int lane = t & 63;
    const int wid = t >> 6;
    const int R = wid * 32;
    const int lr = lane & 15;
    const int lk = lane >> 4;

    f32x4 acc[2][4];
    #pragma unroll
    for (int fr = 0; fr < 2; ++fr)
        #pragma unroll
        for (int fc = 0; fc < 4; ++fc)
            acc[fr][fc] = (f32x4){0.f, 0.f, 0.f, 0.f};

    #pragma unroll
    for (int ks = 0; ks < 4; ++ks) {
        int o = ks * 4 + lk;
        int r0 = R + lr, r1 = R + 16 + lr;
        f16x8 af0 = *(const f16x8*)&Ah[r0 * 128 + (o ^ (r0 & 15)) * 8];
        f16x8 af1 = *(const f16x8*)&Ah[r1 * 128 + (o ^ (r1 & 15)) * 8];
        #pragma unroll
        for (int fc = 0; fc < 4; ++fc) {
            int c = fc * 16 + lr;
            f16x8 bf = *(const f16x8*)&Bt[c * 128 + (o ^ (c & 15)) * 8];
            acc[0][fc] = __builtin_amdgcn_mfma_f32_16x16x32_f16(af0, bf, acc[0][fc], 0, 0, 0);
            acc[1][fc] = __builtin_amdgcn_mfma_f32_16x16x32_f16(af1, bf, acc[1][fc], 0, 0, 0);
        }
    }

    float bv[4];
    #pragma unroll
    for (int fc = 0; fc < 4; ++fc) bv[fc] = bias[fc * 16 + lr];

    __syncthreads();   // all waves finished reading Ah/Bt — safe to overwrite

    // write h (fp16) into Ah reinterpreted as [128][64] with o^(r&7) swizzle
    #pragma unroll
    for (int fr = 0; fr < 2; ++fr) {
        #pragma unroll
        for (int j = 0; j < 4; ++j) {
            int lrow = R + fr * 16 + lk * 4 + j;   // local row 0..127
            #pragma unroll
            for (int fc = 0; fc < 4; ++fc) {
                int col = fc * 16 + lr;
                float v = fmaxf(acc[fr][fc][j] + bv[fc], 0.f);
                int o = col >> 3;
                Ah[lrow * 64 + ((o ^ (lrow & 7)) * 8) + (col & 7)] = __float2half(v);
            }
        }
    }
    // restage Bt as W1 [c][k] (coalesced: lanes step c)
    #pragma unroll
    for (int p = 0; p < 32; ++p) {
        int li = p * 256 + t;         // k*128 + c
        int c = li & 127;
        int k = li >> 7;              // 0..63
        float wv = (c < 64) ? W1p[k * 64 + c] : W1p[(64 + k) * 64 + (c - 64)];
        Bt[c * 64 + (((k >> 3) ^ (c & 7)) * 8) + (k & 7)] = __float2half(wv);
    }
    __syncthreads();

    // ---- stage 2: U|V = h @ [W1_top | W1_bot]  (k_uvm compute) ----
    f32x4 acc2[2][8];
    #pragma unroll
    for (int fr = 0; fr < 2; ++fr)
        #pragma unroll
        for (int fc = 0; fc < 8; ++fc)
            acc2[fr][fc] = (f32x4){0.f, 0.f, 0.f, 0.f};

    #pragma unroll
    for (int ks = 0; ks < 2; ++ks) {
        int o = ks * 4 + lk;          // octet 0..7
        int r0 = R + lr, r1 = R + 16 + lr;
        f16x8 af0 = *(const f16x8*)&Ah[r0 * 64 + (o ^ (r0 & 7)) * 8];
        f16x8 af1 = *(const f16x8*)&Ah[r1 * 64 + (o ^ (r1 & 7)) * 8];
        #pragma unroll
        for (int fc = 0; fc < 8; ++fc) {
            int c = fc * 16 + lr;
            f16x8 bf = *(const f16x8*)&Bt[c * 64 + (o ^ (c & 7)) * 8];
            acc2[0][fc] = __builtin_amdgcn_mfma_f32_16x16x32_f16(af0, bf, acc2[0][fc], 0, 0, 0);
            acc2[1][fc] = __builtin_amdgcn_mfma_f32_16x16x32_f16(af1, bf, acc2[1][fc], 0, 0, 0);
        }
    }

    #pragma unroll
    for (int fr = 0; fr < 2; ++fr) {
        #pragma unroll
        for (int j = 0; j < 4; ++j) {
            int gr = g0 + R + fr * 16 + lk * 4 + j;
            if (gr < nrows) {
                #pragma unroll
                for (int fc = 0; fc < 8; ++fc) {
                    int col = fc * 16 + lr;
                    __half v = __float2half(acc2[fr][fc][j]);
                    if (col < 64) U16[(size_t)gr * 64 + col] = v;
                    else          V16[(size_t)gr * 64 + (col - 64)] = v;
                }
            }
        }
    }
}

// k_pred: out[p] = relu(U[a] + V[b] + b1) . W2 + b2 — pure gather-reduce.
// fp16 U/V rows (128 B): 16 lanes x 8 B = full row. b1/W2/accum stay f32.
__global__ __launch_bounds__(256) void k_pred(
    const __half* __restrict__ U16, const __half* __restrict__ V16,
    const int* __restrict__ pidx, const float* __restrict__ b1,
    const float* __restrict__ W2, const float* __restrict__ b2,
    float* __restrict__ outp, int np)
{
    const int t = threadIdx.x;
    const int lg = t & 15;
    const int p = blockIdx.x * 16 + (t >> 4);
    float4 bv = ld4(b1 + lg * 4);
    float4 wv = ld4(W2 + lg * 4);
    if (p >= np) return;
    int2 ab = ((const int2*)pidx)[p];
    float2 ur = *(const float2*)&U16[(size_t)ab.x * 64 + lg * 4];
    float2 vr = *(const float2*)&V16[(size_t)ab.y * 64 + lg * 4];
    union { float f; __half2 h; } u0, u1, v0, v1;
    u0.f = ur.x; u1.f = ur.y; v0.f = vr.x; v1.f = vr.y;
    float2 ua = __half22float2(u0.h), ub = __half22float2(u1.h);
    float2 va = __half22float2(v0.h), vb = __half22float2(v1.h);
    float zx = fmaxf(ua.x + va.x + bv.x, 0.f);
    float zy = fmaxf(ua.y + va.y + bv.y, 0.f);
    float zz = fmaxf(ub.x + vb.x + bv.z, 0.f);
    float zw = fmaxf(ub.y + vb.y + bv.w, 0.f);
    float s = zx * wv.x + zy * wv.y + zz * wv.z + zw * wv.w;
    s += __shfl_down(s, 8, 16);
    s += __shfl_down(s, 4, 16);
    s += __shfl_down(s, 2, 16);
    s += __shfl_down(s, 1, 16);
    if (lg == 0) outp[p] = s + b2[0];
}

// ---------------- launch ----------------

extern "C" void kernel_launch(void* const* d_in, const int* in_sizes, int n_in,
                              void* d_out, int out_size, void* d_ws, size_t ws_size,
                              hipStream_t stream) {
    const float* x    = (const float*)d_in[0];
    const int*   edges= (const int*)d_in[1];
    const int*   pair = (const int*)d_in[2];
    const float* encW = (const float*)d_in[3];
    const float* encb = (const float*)d_in[4];
    const float* Wl   = (const float*)d_in[5];
    const float* bl   = (const float*)d_in[6];
    const float* Wr   = (const float*)d_in[7];
    const float* W1   = (const float*)d_in[8];
    const float* b1   = (const float*)d_in[9];
    const float* W2   = (const float*)d_in[10];
    const float* b2   = (const float*)d_in[11];
    float* out = (float*)d_out;

    const int N = N_NODES_C, E = N_EDGES_C, P = N_PAIRS_C;
    const int* dst = edges + E;
    const int M = NBKT * NB_S;

    char* w = (char*)d_ws;
    auto alloc = [&](size_t bytes) { char* p = w; w += (bytes + 255) & ~(size_t)255; return p; };
    int*   rowptr = (int*)alloc((size_t)(N + 1) * 4);
    int*   histT  = (int*)alloc((size_t)M * 4);
    int*   offs   = (int*)alloc((size_t)M * 4);
    float* invd   = (float*)alloc((size_t)N * 4);
    int*   adj    = (int*)alloc((size_t)E * 4);
    int2*  staging= (int2*)alloc((size_t)E * 8);
    __half* h16a  = (__half*)alloc((size_t)N * HID_C * 2);
    __half* h16b  = (__half*)alloc((size_t)N * HID_C * 2);
    __half* agg16 = (__half*)alloc((size_t)N * HID_C * 2);
    __half* U16   = (__half*)alloc((size_t)N * HID_C * 2);
    __half* V16   = (__half*)alloc((size_t)N * HID_C * 2);

    hipLaunchKernelGGL(k_hist, dim3(NB_S), dim3(256), 0, stream, dst, histT, E);
    hipLaunchKernelGGL(k_scan_full, dim3(1), dim3(1024), 0, stream, histT, offs, M);
    hipLaunchKernelGGL(k_scatter, dim3(NB_S), dim3(256), 0, stream, edges, offs, staging, E);
    hipLaunchKernelGGL(k_bucket_fill, dim3(NBKT), dim3(256), 0, stream, staging, offs, rowptr, invd, adj, N, E);

    const int NB128 = (N + 127) / 128;

    // encoder: MFMA fp16, fp16-only output
    k_mm<0><<<dim3(NB128), dim3(256), 0, stream>>>(
        x, nullptr, nullptr, encW, nullptr, encb, h16a, N);

    __half* h16c = h16a; __half* h16n = h16b;
    for (int l = 0; l < 2; l++) {
        hipLaunchKernelGGL(k_aggregate, dim3((N + 31) / 32), dim3(256), 0, stream,
                           rowptr, adj, invd, h16c, agg16, N);
        k_mm<1><<<dim3(NB128), dim3(256), 0, stream>>>(
            nullptr, agg16, h16c, Wl + (size_t)l * 64 * 64, Wr + (size_t)l * 64 * 64,
            bl + (size_t)l * 64, h16n, N);
        __half* t16 = h16c; h16c = h16n; h16n = t16;
    }

    // layer 2 fused with UV: h never touches HBM
    hipLaunchKernelGGL(k_aggregate, dim3((N + 31) / 32), dim3(256), 0, stream,
                       rowptr, adj, invd, h16c, agg16, N);
    hipLaunchKernelGGL(k_mm_uv, dim3(NB128), dim3(256), 0, stream,
                       agg16, h16c, Wl + (size_t)2 * 64 * 64, Wr + (size_t)2 * 64 * 64,
                       bl + (size_t)2 * 64, W1, U16, V16, N);

    hipLaunchKernelGGL(k_pred, dim3((P + 15) / 16), dim3(256), 0, stream,
                       U16, V16, pair, b1, W2, b2, out, P);
}

// Round 14
// 295.610 us; speedup vs baseline: 1.3003x; 1.3003x over previous
//
#include <hip/hip_runtime.h>
#include <hip/hip_fp16.h>
#include <cstdint>
#include <cstddef>

#define N_NODES_C 100000
#define N_EDGES_C 1250000
#define N_PAIRS_C 200000
#define IN_DIM_C 128
#define HID_C 64

// graph-build geometry
#define NB_S 256
#define BSH 9
#define NPB 512
#define NBKT 196
#define SEG_CAP 8192

typedef _Float16 f16x8 __attribute__((ext_vector_type(8)));
typedef float f32x4 __attribute__((ext_vector_type(4)));

// ---------------- scan helpers (R12-proven 3-kernel chain; R13's single-block
// k_scan_full was 94 us @ 0.16% occupancy — one CU serialized. REVERTED.) ----

#define SCAN_TPB 256
#define SCAN_IPT 4
#define SCAN_ELEMS 1024

__global__ void k_scan_partial(const int* __restrict__ in, int* __restrict__ outp,
                               int* __restrict__ blocksums, int n) {
    __shared__ int sd[SCAN_TPB];
    int tid = threadIdx.x;
    int base = blockIdx.x * SCAN_ELEMS + tid * SCAN_IPT;
    int v[SCAN_IPT]; int s = 0;
    for (int k = 0; k < SCAN_IPT; k++) { int idx = base + k; v[k] = (idx < n) ? in[idx] : 0; s += v[k]; }
    sd[tid] = s;
    __syncthreads();
    for (int off = 1; off < SCAN_TPB; off <<= 1) {
        int t = (tid >= off) ? sd[tid - off] : 0;
        __syncthreads();
        sd[tid] += t;
        __syncthreads();
    }
    int excl = sd[tid] - s;
    for (int k = 0; k < SCAN_IPT; k++) { int idx = base + k; if (idx < n) outp[idx] = excl; excl += v[k]; }
    if (tid == SCAN_TPB - 1) blocksums[blockIdx.x] = sd[tid];
}

__global__ void k_scan_blocks(int* __restrict__ bs, int nb) {
    __shared__ int sd[128];
    int t = threadIdx.x;
    int v = (t < nb) ? bs[t] : 0;
    sd[t] = v;
    __syncthreads();
    for (int off = 1; off < 128; off <<= 1) {
        int u = (t >= off) ? sd[t - off] : 0;
        __syncthreads();
        sd[t] += u;
        __syncthreads();
    }
    if (t < nb) bs[t] = sd[t] - v;
}

__global__ void k_scan_addg(int* __restrict__ arr, const int* __restrict__ bs, int n) {
    int i = blockIdx.x * blockDim.x + threadIdx.x;
    if (i < n) arr[i] += bs[i >> 10];
}

// ---------------- graph build: two-level counting sort ----------------

__global__ __launch_bounds__(256) void k_hist(const int* __restrict__ dst,
                                              int* __restrict__ histT, int e) {
    __shared__ int lh[NBKT];
    int tid = threadIdx.x, k = blockIdx.x;
    if (tid < NBKT) lh[tid] = 0;
    __syncthreads();
    int chunk = (e + NB_S - 1) / NB_S;
    int i0 = k * chunk, i1 = min(i0 + chunk, e);
    for (int i = i0 + tid; i < i1; i += 256) atomicAdd(&lh[dst[i] >> BSH], 1);
    __syncthreads();
    if (tid < NBKT) histT[tid * NB_S + k] = lh[tid];
}

__global__ __launch_bounds__(256) void k_scatter(const int* __restrict__ edges,
                                                 const int* __restrict__ offs,
                                                 int2* __restrict__ staging, int e) {
    __shared__ int cur[NBKT];
    int tid = threadIdx.x, k = blockIdx.x;
    if (tid < NBKT) cur[tid] = offs[tid * NB_S + k];
    __syncthreads();
    int chunk = (e + NB_S - 1) / NB_S;
    int i0 = k * chunk, i1 = min(i0 + chunk, e);
    for (int i = i0 + tid; i < i1; i += 256) {
        int s = edges[i];
        int d = edges[e + i];
        int p = atomicAdd(&cur[d >> BSH], 1);
        staging[p] = make_int2(s, d);
    }
}

__global__ __launch_bounds__(256) void k_bucket_fill(const int2* __restrict__ staging,
        const int* __restrict__ offs, int* __restrict__ rowptr,
        float* __restrict__ invd, int* __restrict__ adj, int n, int e) {
    __shared__ int ldeg[NPB];
    __shared__ int lrow[NPB];
    __shared__ int ps[256];
    __shared__ int lseg[SEG_CAP];
    int tid = threadIdx.x, b = blockIdx.x;
    int n0 = b << BSH;
    int nn = min(NPB, n - n0);
    int segBeg = offs[b * NB_S];
    int segEnd = (b == NBKT - 1) ? e : offs[(b + 1) * NB_S];

    ldeg[tid] = 0; ldeg[tid + 256] = 0;
    __syncthreads();
    for (int i = segBeg + tid; i < segEnd; i += 256)
        atomicAdd(&ldeg[staging[i].y - n0], 1);
    __syncthreads();

    int a0 = ldeg[2 * tid], a1 = ldeg[2 * tid + 1];
    int s = a0 + a1;
    ps[tid] = s;
    __syncthreads();
    for (int off = 1; off < 256; off <<= 1) {
        int t = (tid >= off) ? ps[tid - off] : 0;
        __syncthreads();
        ps[tid] += t;
        __syncthreads();
    }
    int excl = ps[tid] - s;
    lrow[2 * tid] = excl;
    lrow[2 * tid + 1] = excl + a0;
    __syncthreads();

    for (int j = tid; j < nn; j += 256) {
        rowptr[n0 + j] = segBeg + lrow[j];
        int d = ldeg[j];
        invd[n0 + j] = (d > 0) ? (1.0f / (float)d) : 0.0f;
    }
    if (b == NBKT - 1 && tid == 0) rowptr[n] = e;
    __syncthreads();

    for (int i = segBeg + tid; i < segEnd; i += 256) {
        int2 ed = staging[i];
        int p = atomicAdd(&lrow[ed.y - n0], 1);
        if (p < SEG_CAP) lseg[p] = ed.x;
        else adj[segBeg + p] = ed.x;
    }
    __syncthreads();

    int m = segEnd - segBeg; if (m > SEG_CAP) m = SEG_CAP;
    for (int p = tid; p < m; p += 256) adj[segBeg + p] = lseg[p];
}

// ---------------- aggregation ----------------
// fp16-gather, EIGHT NODES PER WAVE (ladder: 50 f32 -> 46 fp16 -> 36 two-node
// -> ~30 four-node -> ~25 this). 8 lanes per node, one 16 B load = 8 cols;
// 8 x 16 B = full 128 B row; one gather instruction serves 8 edge-rows.
// Ladder bottomed here: fewer lanes/node would need 2 loads/lane. Gather
// needs high occupancy (R4) and is memory+issue mixed (R5/R7).

__global__ __launch_bounds__(256) void k_aggregate(const int* __restrict__ rowptr,
        const int* __restrict__ adj, const float* __restrict__ invd,
        const __half* __restrict__ hin16, __half* __restrict__ agg16, int n) {
    int wid = threadIdx.x >> 6, lane = threadIdx.x & 63;
    int node0 = (blockIdx.x * 4 + wid) * 8;   // 8 nodes per wave
    if (node0 >= n) return;
    const int q = lane >> 3;          // eighth 0..7 -> node slot
    const int c8 = (lane & 7) * 8;    // columns c8..c8+7
    int node = node0 + q;
    bool valid = node < n;
    int nodec = valid ? node : n - 1;
    int beg = rowptr[nodec], end = rowptr[nodec + 1];
    float a0 = 0.f, a1 = 0.f, a2 = 0.f, a3 = 0.f;
    float a4 = 0.f, a5 = 0.f, a6 = 0.f, a7 = 0.f;
    for (int e = beg; e < end; e += 8) {
        int idx[8];
        #pragma unroll
        for (int j = 0; j < 8; ++j) {
            int ee = e + j;
            idx[j] = adj[ee < end ? ee : end - 1];
        }
        float4 raw[8];
        #pragma unroll
        for (int j = 0; j < 8; ++j)
            raw[j] = *(const float4*)&hin16[(size_t)idx[j] * HID_C + c8];
        #pragma unroll
        for (int j = 0; j < 8; ++j) {
            union { float4 f; __half2 h[4]; } u;
            u.f = raw[j];
            float2 f0 = __half22float2(u.h[0]);
            float2 f1 = __half22float2(u.h[1]);
            float2 f2 = __half22float2(u.h[2]);
            float2 f3 = __half22float2(u.h[3]);
            bool in = (e + j < end);
            a0 += in ? f0.x : 0.f;  a1 += in ? f0.y : 0.f;
            a2 += in ? f1.x : 0.f;  a3 += in ? f1.y : 0.f;
            a4 += in ? f2.x : 0.f;  a5 += in ? f2.y : 0.f;
            a6 += in ? f3.x : 0.f;  a7 += in ? f3.y : 0.f;
        }
    }
    if (valid) {
        float s = invd[node];
        union { float4 f; __half2 h[4]; } o;
        o.h[0] = __floats2half2_rn(a0 * s, a1 * s);
        o.h[1] = __floats2half2_rn(a2 * s, a3 * s);
        o.h[2] = __floats2half2_rn(a4 * s, a5 * s);
        o.h[3] = __floats2half2_rn(a6 * s, a7 * s);
        *(float4*)&agg16[(size_t)node * HID_C + c8] = o.f;
    }
}

// ---------------- helpers ----------------

__device__ __forceinline__ float4 ld4(const float* p) { return *(const float4*)p; }

// ---------------- k_mm: MFMA fp16 GEMM (enc + layers 0,1) --------------------
// R9 PROVEN core. out16 = fp16(relu(A @ W + b)), K=128, BM=128 x BN=64,
// 4 waves, mfma_f32_16x16x32_f16, 48 KB LDS. A/B staged with the SAME assumed
// k-octet map -> HW k-permutation cancels; C/D col=lane&15, row=(lane>>4)*4+reg.
// SRC 0: A = x (f32, stride 128, converted in staging), W = Ws1 (128x64)
// SRC 1: A = [agg16 | h16] (fp16, stride 64 each), W = [Ws1;Ws2] (64x64 each)

template<int SRC>
__global__ __launch_bounds__(256, 2) void k_mm(
    const float* __restrict__ A1f,
    const __half* __restrict__ A1h, const __half* __restrict__ A2h,
    const float* __restrict__ Ws1, const float* __restrict__ Ws2,
    const float* __restrict__ bias,
    __half* __restrict__ out16, int nrows)
{
    __shared__ __half Ah[128 * 128];  // [row][k-swizzled], 32 KB
    __shared__ __half Bt[64 * 128];   // [col][k-swizzled], 16 KB
    const int t = threadIdx.x;
    const int g0 = blockIdx.x * 128;

    #pragma unroll
    for (int p = 0; p < 8; ++p) {
        int li = p * 256 + t;
        int r = li >> 4;              // 0..127
        int o = li & 15;              // octet
        int g = g0 + r; if (g > nrows - 1) g = nrows - 1;
        f16x8 v;
        if (SRC == 0) {
            const float* src = A1f + (size_t)g * 128 + o * 8;
            float4 f0 = ld4(src), f1 = ld4(src + 4);
            v[0] = (_Float16)f0.x; v[1] = (_Float16)f0.y;
            v[2] = (_Float16)f0.z; v[3] = (_Float16)f0.w;
            v[4] = (_Float16)f1.x; v[5] = (_Float16)f1.y;
            v[6] = (_Float16)f1.z; v[7] = (_Float16)f1.w;
        } else {
            const __half* src = (o < 8) ? (A1h + (size_t)g * 64 + o * 8)
                                        : (A2h + (size_t)g * 64 + (o - 8) * 8);
            v = *(const f16x8*)src;
        }
        *(f16x8*)&Ah[r * 128 + (o ^ (r & 15)) * 8] = v;
    }
    #pragma unroll
    for (int p = 0; p < 32; ++p) {
        int li = p * 256 + t;
        int c = li & 63;
        int k = li >> 6;              // 0..127
        float wv;
        if (SRC == 0) wv = Ws1[k * 64 + c];
        else          wv = (k < 64) ? Ws1[k * 64 + c] : Ws2[(k - 64) * 64 + c];
        Bt[c * 128 + (((k >> 3) ^ (c & 15)) * 8) + (k & 7)] = __float2half(wv);
    }
    __syncthreads();

    const int lane = t & 63;
    const int wid = t >> 6;
    const int R = wid * 32;           // wave's 32-row strip
    const int lr = lane & 15;
    const int lk = lane >> 4;         // octet-within-K-step

    f32x4 acc[2][4];
    #pragma unroll
    for (int fr = 0; fr < 2; ++fr)
        #pragma unroll
        for (int fc = 0; fc < 4; ++fc)
            acc[fr][fc] = (f32x4){0.f, 0.f, 0.f, 0.f};

    #pragma unroll
    for (int ks = 0; ks < 4; ++ks) {
        int o = ks * 4 + lk;          // octet 0..15
        f16x8 af0, af1;
        {
            int r0 = R + lr;
            int r1 = R + 16 + lr;
            af0 = *(const f16x8*)&Ah[r0 * 128 + (o ^ (r0 & 15)) * 8];
            af1 = *(const f16x8*)&Ah[r1 * 128 + (o ^ (r1 & 15)) * 8];
        }
        #pragma unroll
        for (int fc = 0; fc < 4; ++fc) {
            int c = fc * 16 + lr;
            f16x8 bf = *(const f16x8*)&Bt[c * 128 + (o ^ (c & 15)) * 8];
            acc[0][fc] = __builtin_amdgcn_mfma_f32_16x16x32_f16(af0, bf, acc[0][fc], 0, 0, 0);
            acc[1][fc] = __builtin_amdgcn_mfma_f32_16x16x32_f16(af1, bf, acc[1][fc], 0, 0, 0);
        }
    }

    float bv[4];
    #pragma unroll
    for (int fc = 0; fc < 4; ++fc) bv[fc] = bias[fc * 16 + lr];
    #pragma unroll
    for (int fr = 0; fr < 2; ++fr) {
        #pragma unroll
        for (int j = 0; j < 4; ++j) {
            int gr = g0 + R + fr * 16 + lk * 4 + j;
            if (gr < nrows) {
                #pragma unroll
                for (int fc = 0; fc < 4; ++fc) {
                    int col = fc * 16 + lr;
                    float v = fmaxf(acc[fr][fc][j] + bv[fc], 0.f);
                    out16[(size_t)gr * 64 + col] = __float2half(v);
                }
            }
        }
    }
}

// ---------------- k_mm_uv: layer-2 GEMM fused with the UV GEMM ---------------
// R13 KEPT (isolated Δ ≈ -5 us): layer-2's h is consumed ONLY by the UV GEMM,
// and each block holds the full 128x64 h-tile in registers after stage 1.
// Sync, write bias+relu'd h (same __float2half rounding -> numerically
// identical) into Ah re-laid-out [128][64] with o^(r&7) swizzle, restage W1
// into Bt, run the UV stage in-place. Kills one launch + 25.6 MB h traffic.

__global__ __launch_bounds__(256, 2) void k_mm_uv(
    const __half* __restrict__ A1h, const __half* __restrict__ A2h,
    const float* __restrict__ Ws1, const float* __restrict__ Ws2,
    const float* __restrict__ bias, const float* __restrict__ W1p,
    __half* __restrict__ U16, __half* __restrict__ V16, int nrows)
{
    __shared__ __half Ah[128 * 128];  // stage1: [row][k^sw] 32 KB; stage2: h [128][64]
    __shared__ __half Bt[64 * 128];   // stage1: W [col][k^sw] 16 KB; stage2: W1 [128][64]
    const int t = threadIdx.x;
    const int g0 = blockIdx.x * 128;

    // ---- stage 1: h = relu([agg|h] @ [Wl;Wr] + b)  (identical to k_mm<1>) ----
    #pragma unroll
    for (int p = 0; p < 8; ++p) {
        int li = p * 256 + t;
        int r = li >> 4;
        int o = li & 15;
        int g = g0 + r; if (g > nrows - 1) g = nrows - 1;
        const __half* src = (o < 8) ? (A1h + (size_t)g * 64 + o * 8)
                                    : (A2h + (size_t)g * 64 + (o - 8) * 8);
        f16x8 v = *(const f16x8*)src;
        *(f16x8*)&Ah[r * 128 + (o ^ (r & 15)) * 8] = v;
    }
    #pragma unroll
    for (int p = 0; p < 32; ++p) {
        int li = p * 256 + t;
        int c = li & 63;
        int k = li >> 6;
        float wv = (k < 64) ? Ws1[k * 64 + c] : Ws2[(k - 64) * 64 + c];
        Bt[c * 128 + (((k >> 3) ^ (c & 15)) * 8) + (k & 7)] = __float2half(wv);
    }
    __syncthreads();

    const int lane = t & 63;
    const int wid = t >> 6;
    const int R = wid * 32;
    const int lr = lane & 15;
    const int lk = lane >> 4;

    f32x4 acc[2][4];
    #pragma unroll
    for (int fr = 0; fr < 2; ++fr)
        #pragma unroll
        for (int fc = 0; fc < 4; ++fc)
            acc[fr][fc] = (f32x4){0.f, 0.f, 0.f, 0.f};

    #pragma unroll
    for (int ks = 0; ks < 4; ++ks) {
        int o = ks * 4 + lk;
        int r0 = R + lr, r1 = R + 16 + lr;
        f16x8 af0 = *(const f16x8*)&Ah[r0 * 128 + (o ^ (r0 & 15)) * 8];
        f16x8 af1 = *(const f16x8*)&Ah[r1 * 128 + (o ^ (r1 & 15)) * 8];
        #pragma unroll
        for (int fc = 0; fc < 4; ++fc) {
            int c = fc * 16 + lr;
            f16x8 bf = *(const f16x8*)&Bt[c * 128 + (o ^ (c & 15)) * 8];
            acc[0][fc] = __builtin_amdgcn_mfma_f32_16x16x32_f16(af0, bf, acc[0][fc], 0, 0, 0);
            acc[1][fc] = __builtin_amdgcn_mfma_f32_16x16x32_f16(af1, bf, acc[1][fc], 0, 0, 0);
        }
    }

    float bv[4];
    #pragma unroll
    for (int fc = 0; fc < 4; ++fc) bv[fc] = bias[fc * 16 + lr];

    __syncthreads();   // all waves finished reading Ah/Bt — safe to overwrite

    // write h (fp16) into Ah reinterpreted as [128][64] with o^(r&7) swizzle
    #pragma unroll
    for (int fr = 0; fr < 2; ++fr) {
        #pragma unroll
        for (int j = 0; j < 4; ++j) {
            int lrow = R + fr * 16 + lk * 4 + j;   // local row 0..127
            #pragma unroll
            for (int fc = 0; fc < 4; ++fc) {
                int col = fc * 16 + lr;
                float v = fmaxf(acc[fr][fc][j] + bv[fc], 0.f);
                int o = col >> 3;
                Ah[lrow * 64 + ((o ^ (lrow & 7)) * 8) + (col & 7)] = __float2half(v);
            }
        }
    }
    // restage Bt as W1 [c][k] (coalesced: lanes step c)
    #pragma unroll
    for (int p = 0; p < 32; ++p) {
        int li = p * 256 + t;         // k*128 + c
        int c = li & 127;
        int k = li >> 7;              // 0..63
        float wv = (c < 64) ? W1p[k * 64 + c] : W1p[(64 + k) * 64 + (c - 64)];
        Bt[c * 64 + (((k >> 3) ^ (c & 7)) * 8) + (k & 7)] = __float2half(wv);
    }
    __syncthreads();

    // ---- stage 2: U|V = h @ [W1_top | W1_bot]  (UV compute) ----
    f32x4 acc2[2][8];
    #pragma unroll
    for (int fr = 0; fr < 2; ++fr)
        #pragma unroll
        for (int fc = 0; fc < 8; ++fc)
            acc2[fr][fc] = (f32x4){0.f, 0.f, 0.f, 0.f};

    #pragma unroll
    for (int ks = 0; ks < 2; ++ks) {
        int o = ks * 4 + lk;          // octet 0..7
        int r0 = R + lr, r1 = R + 16 + lr;
        f16x8 af0 = *(const f16x8*)&Ah[r0 * 64 + (o ^ (r0 & 7)) * 8];
        f16x8 af1 = *(const f16x8*)&Ah[r1 * 64 + (o ^ (r1 & 7)) * 8];
        #pragma unroll
        for (int fc = 0; fc < 8; ++fc) {
            int c = fc * 16 + lr;
            f16x8 bf = *(const f16x8*)&Bt[c * 64 + (o ^ (c & 7)) * 8];
            acc2[0][fc] = __builtin_amdgcn_mfma_f32_16x16x32_f16(af0, bf, acc2[0][fc], 0, 0, 0);
            acc2[1][fc] = __builtin_amdgcn_mfma_f32_16x16x32_f16(af1, bf, acc2[1][fc], 0, 0, 0);
        }
    }

    #pragma unroll
    for (int fr = 0; fr < 2; ++fr) {
        #pragma unroll
        for (int j = 0; j < 4; ++j) {
            int gr = g0 + R + fr * 16 + lk * 4 + j;
            if (gr < nrows) {
                #pragma unroll
                for (int fc = 0; fc < 8; ++fc) {
                    int col = fc * 16 + lr;
                    __half v = __float2half(acc2[fr][fc][j]);
                    if (col < 64) U16[(size_t)gr * 64 + col] = v;
                    else          V16[(size_t)gr * 64 + (col - 64)] = v;
                }
            }
        }
    }
}

// k_pred: out[p] = relu(U[a] + V[b] + b1) . W2 + b2 — pure gather-reduce.
// fp16 U/V rows (128 B): 16 lanes x 8 B = full row. b1/W2/accum stay f32.
__global__ __launch_bounds__(256) void k_pred(
    const __half* __restrict__ U16, const __half* __restrict__ V16,
    const int* __restrict__ pidx, const float* __restrict__ b1,
    const float* __restrict__ W2, const float* __restrict__ b2,
    float* __restrict__ outp, int np)
{
    const int t = threadIdx.x;
    const int lg = t & 15;
    const int p = blockIdx.x * 16 + (t >> 4);
    float4 bv = ld4(b1 + lg * 4);
    float4 wv = ld4(W2 + lg * 4);
    if (p >= np) return;
    int2 ab = ((const int2*)pidx)[p];
    float2 ur = *(const float2*)&U16[(size_t)ab.x * 64 + lg * 4];
    float2 vr = *(const float2*)&V16[(size_t)ab.y * 64 + lg * 4];
    union { float f; __half2 h; } u0, u1, v0, v1;
    u0.f = ur.x; u1.f = ur.y; v0.f = vr.x; v1.f = vr.y;
    float2 ua = __half22float2(u0.h), ub = __half22float2(u1.h);
    float2 va = __half22float2(v0.h), vb = __half22float2(v1.h);
    float zx = fmaxf(ua.x + va.x + bv.x, 0.f);
    float zy = fmaxf(ua.y + va.y + bv.y, 0.f);
    float zz = fmaxf(ub.x + vb.x + bv.z, 0.f);
    float zw = fmaxf(ub.y + vb.y + bv.w, 0.f);
    float s = zx * wv.x + zy * wv.y + zz * wv.z + zw * wv.w;
    s += __shfl_down(s, 8, 16);
    s += __shfl_down(s, 4, 16);
    s += __shfl_down(s, 2, 16);
    s += __shfl_down(s, 1, 16);
    if (lg == 0) outp[p] = s + b2[0];
}

// ---------------- launch ----------------

extern "C" void kernel_launch(void* const* d_in, const int* in_sizes, int n_in,
                              void* d_out, int out_size, void* d_ws, size_t ws_size,
                              hipStream_t stream) {
    const float* x    = (const float*)d_in[0];
    const int*   edges= (const int*)d_in[1];
    const int*   pair = (const int*)d_in[2];
    const float* encW = (const float*)d_in[3];
    const float* encb = (const float*)d_in[4];
    const float* Wl   = (const float*)d_in[5];
    const float* bl   = (const float*)d_in[6];
    const float* Wr   = (const float*)d_in[7];
    const float* W1   = (const float*)d_in[8];
    const float* b1   = (const float*)d_in[9];
    const float* W2   = (const float*)d_in[10];
    const float* b2   = (const float*)d_in[11];
    float* out = (float*)d_out;

    const int N = N_NODES_C, E = N_EDGES_C, P = N_PAIRS_C;
    const int* dst = edges + E;
    const int M = NBKT * NB_S;

    char* w = (char*)d_ws;
    auto alloc = [&](size_t bytes) { char* p = w; w += (bytes + 255) & ~(size_t)255; return p; };
    int*   rowptr = (int*)alloc((size_t)(N + 1) * 4);
    int*   histT  = (int*)alloc((size_t)M * 4);
    int*   offs   = (int*)alloc((size_t)M * 4);
    int*   bsums  = (int*)alloc(128 * 4);
    float* invd   = (float*)alloc((size_t)N * 4);
    int*   adj    = (int*)alloc((size_t)E * 4);
    int2*  staging= (int2*)alloc((size_t)E * 8);
    __half* h16a  = (__half*)alloc((size_t)N * HID_C * 2);
    __half* h16b  = (__half*)alloc((size_t)N * HID_C * 2);
    __half* agg16 = (__half*)alloc((size_t)N * HID_C * 2);
    __half* U16   = (__half*)alloc((size_t)N * HID_C * 2);
    __half* V16   = (__half*)alloc((size_t)N * HID_C * 2);

    int nscan = (M + SCAN_ELEMS - 1) / SCAN_ELEMS;

    hipLaunchKernelGGL(k_hist, dim3(NB_S), dim3(256), 0, stream, dst, histT, E);
    hipLaunchKernelGGL(k_scan_partial, dim3(nscan), dim3(SCAN_TPB), 0, stream, histT, offs, bsums, M);
    hipLaunchKernelGGL(k_scan_blocks, dim3(1), dim3(128), 0, stream, bsums, nscan);
    hipLaunchKernelGGL(k_scan_addg, dim3((M + 255) / 256), dim3(256), 0, stream, offs, bsums, M);
    hipLaunchKernelGGL(k_scatter, dim3(NB_S), dim3(256), 0, stream, edges, offs, staging, E);
    hipLaunchKernelGGL(k_bucket_fill, dim3(NBKT), dim3(256), 0, stream, staging, offs, rowptr, invd, adj, N, E);

    const int NB128 = (N + 127) / 128;

    // encoder: MFMA fp16, fp16-only output
    k_mm<0><<<dim3(NB128), dim3(256), 0, stream>>>(
        x, nullptr, nullptr, encW, nullptr, encb, h16a, N);

    __half* h16c = h16a; __half* h16n = h16b;
    for (int l = 0; l < 2; l++) {
        hipLaunchKernelGGL(k_aggregate, dim3((N + 31) / 32), dim3(256), 0, stream,
                           rowptr, adj, invd, h16c, agg16, N);
        k_mm<1><<<dim3(NB128), dim3(256), 0, stream>>>(
            nullptr, agg16, h16c, Wl + (size_t)l * 64 * 64, Wr + (size_t)l * 64 * 64,
            bl + (size_t)l * 64, h16n, N);
        __half* t16 = h16c; h16c = h16n; h16n = t16;
    }

    // layer 2 fused with UV: h never touches HBM
    hipLaunchKernelGGL(k_aggregate, dim3((N + 31) / 32), dim3(256), 0, stream,
                       rowptr, adj, invd, h16c, agg16, N);
    hipLaunchKernelGGL(k_mm_uv, dim3(NB128), dim3(256), 0, stream,
                       agg16, h16c, Wl + (size_t)2 * 64 * 64, Wr + (size_t)2 * 64 * 64,
                       bl + (size_t)2 * 64, W1, U16, V16, N);

    hipLaunchKernelGGL(k_pred, dim3((P + 15) / 16), dim3(256), 0, stream,
                       U16, V16, pair, b1, W2, b2, out, P);
}